// Round 6
// baseline (235.178 us; speedup 1.0000x reference)
//
#include <hip/hip_runtime.h>
#include <math.h>

// Dims (fixed by the problem)
#define NB     16
#define NCIN   384
#define NHD    24
#define NDIM   96            // HEADS*HD
#define NSTR   5
#define NDT    480           // NSTR*NDIM

// ---------------------------------------------------------------------------
// Single cooperative kernel. 256 blocks (1/CU), 256 threads.
// block g: b = g>>4 (batch), sub = g&15 (role within batch group).
// Phase A: pool 24 planes (c = sub*24..+23)            -> x8[b]
// Phase B: proj tile d0=(sub&7)*64, pix0=(sub>>3)*32   -> y8[b]
// Phase C: (sub<4) cluster head=sub                    -> o8[b]
// Phase D: proj2 + upsample, o0 = sub*24               -> out[b]
// Group barriers: per-b atomic counters in ws (memset to 0 each call).
// LDS: one union block, max phase D = 10008 floats (40 KB); 1 block/CU.
// ---------------------------------------------------------------------------

__device__ __forceinline__ void group_barrier(int* c, int target) {
    __threadfence();
    __syncthreads();
    if (threadIdx.x == 0) {
        __hip_atomic_fetch_add(c, 1, __ATOMIC_RELEASE, __HIP_MEMORY_SCOPE_AGENT);
        while (__hip_atomic_load(c, __ATOMIC_ACQUIRE, __HIP_MEMORY_SCOPE_AGENT) < target)
            __builtin_amdgcn_s_sleep(2);
    }
    __syncthreads();
    __threadfence();
}

__global__ void __launch_bounds__(256) k_fused(const float* __restrict__ x,
                                               const float* __restrict__ W1,
                                               const float* __restrict__ b1,
                                               const float* __restrict__ W2,
                                               const float* __restrict__ b2,
                                               const float* __restrict__ salpha,
                                               const float* __restrict__ sbeta,
                                               float* __restrict__ out,
                                               float* __restrict__ x8,
                                               float* __restrict__ y8,
                                               float* __restrict__ o8,
                                               int* __restrict__ flags) {
    __shared__ __align__(16) float smem[10100];
    const int g   = blockIdx.x;
    const int b   = g >> 4;
    const int sub = g & 15;
    const int tid = threadIdx.x;
    int* cnt = flags + b * 3;

    // ================= Phase A: pool 24 planes =================
    {
        // part[row][chunk], pitch 17
        #define PART(r,cc) smem[(r)*17+(cc)]
        const int chunk = tid & 15;
        const int rloc  = tid >> 4;
        for (int i = 0; i < 24; ++i) {
            const int c = sub * 24 + i;
            const float4* xp = reinterpret_cast<const float4*>(x + ((size_t)(b * 384 + c)) * 4096);
#pragma unroll
            for (int rr = 0; rr < 4; ++rr) {
                int row = rr * 16 + rloc;
                float4 v = xp[rr * 256 + tid];
                PART(row, chunk) = v.x + v.y + v.z + v.w;
            }
            __syncthreads();
            if (tid < 64) {
                int py = tid >> 3, px = tid & 7;
                float s = 0.f;
#pragma unroll
                for (int r = 0; r < 8; ++r)
                    s += PART(py * 8 + r, px * 2) + PART(py * 8 + r, px * 2 + 1);
                x8[(size_t)(b * 384 + c) * 64 + tid] = s * (1.f / 64.f);
            }
            __syncthreads();
        }
        #undef PART
    }
    group_barrier(cnt + 0, 16);

    // ================= Phase B: proj (32 pix x 64 d tile) =================
    {
        #define PAL(c,p) smem[(c)*32+(p)]            // [64][32]
        #define PBL(c,d) smem[2048+(c)*64+(d)]       // [64][64]
        const int pix0 = (sub >> 3) * 32;
        const int d0   = (sub & 7) * 64;
        const int pxg  = (tid & 15) * 2;
        const int dg   = (tid >> 4) * 4;
        float acc[2][4] = {};
        for (int c0 = 0; c0 < 384; c0 += 64) {
            __syncthreads();
#pragma unroll
            for (int i = 0; i < 2; ++i) {
                int f = tid + i * 256;
                int c = f >> 3, pg = f & 7;
                *reinterpret_cast<float4*>(&PAL(c, pg * 4)) =
                    *reinterpret_cast<const float4*>(&x8[(size_t)(b * 384 + c0 + c) * 64 + pix0 + pg * 4]);
            }
#pragma unroll
            for (int i = 0; i < 4; ++i) {
                int f = tid + i * 256;
                int c = f >> 4, jg = f & 15;
                int d = d0 + jg * 4;
                float4 v = make_float4(0.f, 0.f, 0.f, 0.f);
                if (d < NDT) v = *reinterpret_cast<const float4*>(&W1[(c0 + c) * NDT + d]);
                *reinterpret_cast<float4*>(&PBL(c, jg * 4)) = v;
            }
            __syncthreads();
#pragma unroll 8
            for (int c = 0; c < 64; ++c) {
                float2 a = *reinterpret_cast<const float2*>(&PAL(c, pxg));
                float4 w = *reinterpret_cast<const float4*>(&PBL(c, dg));
                acc[0][0] += a.x * w.x; acc[0][1] += a.x * w.y;
                acc[0][2] += a.x * w.z; acc[0][3] += a.x * w.w;
                acc[1][0] += a.y * w.x; acc[1][1] += a.y * w.y;
                acc[1][2] += a.y * w.z; acc[1][3] += a.y * w.w;
            }
        }
        if (d0 + dg < NDT) {
            float4 bv = *reinterpret_cast<const float4*>(&b1[d0 + dg]);
#pragma unroll
            for (int p = 0; p < 2; ++p) {
                int pix = pix0 + pxg + p;
                float4 v = make_float4(acc[p][0] + bv.x, acc[p][1] + bv.y,
                                       acc[p][2] + bv.z, acc[p][3] + bv.w);
                *reinterpret_cast<float4*>(&y8[(size_t)(b * 64 + pix) * NDT + d0 + dg]) = v;
            }
        }
        #undef PAL
        #undef PBL
    }
    group_barrier(cnt + 1, 16);

    // ================= Phase C: cluster (sub<4 -> head=sub) =================
    if (sub < 4) {
        #define SL(s,p,c)  smem[(s)*1600+(p)*25+(c)]
        #define Y2S(s,m,c) smem[8000+((s)*4+(m))*24+(c)]
        #define WBM(i,n,m) smem[8480+((i)*64+(n))*5+(m)]
        #define AGG(mm,c)  smem[9120+(mm)*25+(c)]
        #define ANL(mm,c)  smem[9320+(mm)*24+(c)]
        #define NRM(mm)    smem[9512+(mm)]
        const int Bi = b, h = sub;
        const int lane = tid & 63, wid = tid >> 6;

        for (int idx = tid; idx < 5 * 64 * 6; idx += 256) {
            int q = idx % 6;
            int row = idx / 6;
            int pix = row & 63, s = row >> 6;
            float4 v = *reinterpret_cast<const float4*>(
                &y8[(size_t)(Bi * 64 + pix) * NDT + s * NDIM + h * NHD + q * 4]);
            int c = q * 4;
            SL(s, pix, c)     = v.x;
            SL(s, pix, c + 1) = v.y;
            SL(s, pix, c + 2) = v.z;
            SL(s, pix, c + 3) = v.w;
        }
        __syncthreads();
        for (int idx = tid; idx < 5 * 4 * 24; idx += 256) {
            int c = idx % 24;
            int m = (idx / 24) & 3;
            int s = idx / 96;
            int my = m >> 1, mx = m & 1;
            float acc = 0.f;
#pragma unroll
            for (int ry = 0; ry < 4; ++ry)
#pragma unroll
                for (int rx = 0; rx < 4; ++rx)
                    acc += SL(s, (my * 4 + ry) * 8 + mx * 4 + rx, c);
            Y2S(s, m, c) = acc * (1.f / 16.f);
        }
        __syncthreads();
        if (wid < 2) {
            const int i = wid, ks = 1 + 2 * i;
            float ka[24];
            float sumk2 = 0.f;
#pragma unroll
            for (int c = 0; c < 24; ++c) { ka[c] = SL(ks, lane, c); sumk2 += ka[c] * ka[c]; }
            float sim[4];
#pragma unroll
            for (int m = 0; m < 4; ++m) {
                float kc2 = 0.f, dt = 0.f;
#pragma unroll
                for (int c = 0; c < 24; ++c) {
                    float kv = Y2S(ks, m, c);
                    kc2 += kv * kv; dt += kv * ka[c];
                }
                sim[m] = 2.f * dt - kc2 - sumk2;
            }
            float w[4];
            if (i == 0) {
                int am = 0; float bv = sim[0];
#pragma unroll
                for (int m = 1; m < 4; ++m) if (sim[m] > bv) { bv = sim[m]; am = m; }
#pragma unroll
                for (int m = 0; m < 4; ++m) w[m] = (m == am) ? 1.f : 0.f;
            } else {
                float mx = fmaxf(fmaxf(sim[0], sim[1]), fmaxf(sim[2], sim[3]));
                float sum = 0.f;
#pragma unroll
                for (int m = 0; m < 4; ++m) { w[m] = expf(sim[m] - mx); sum += w[m]; }
                float inv = 1.f / sum;
#pragma unroll
                for (int m = 0; m < 4; ++m) w[m] *= inv;
            }
#pragma unroll
            for (int m = 0; m < 4; ++m) WBM(i, lane, m) = w[m];
        }
        __syncthreads();
        if (tid < 200) {
            int i = tid / 100, rem = tid % 100;
            int m = rem / 25, c = rem % 25;
            int vs = 2 + 2 * i;
            float s = 0.f;
#pragma unroll 8
            for (int n = 0; n < 64; ++n) {
                float wv = WBM(i, n, m);
                s += (c < 24) ? wv * SL(vs, n, c) : wv;
            }
            AGG(i * 4 + m, c) = s;
        }
        __syncthreads();
        if (tid < 192) {
            int mm = tid / 24, c = tid % 24;
            int i = mm >> 2, m = mm & 3;
            AGG(mm, c) = (Y2S(2 + 2 * i, m, c) + AGG(mm, c)) / (1.f + AGG(mm, 24));
        }
        __syncthreads();
        if (tid < 8) {
            float s = 0.f;
#pragma unroll
            for (int c = 0; c < 24; ++c) s += AGG(tid, c) * AGG(tid, c);
            NRM(tid) = sqrtf(s) + 1e-6f;
        }
        __syncthreads();
        if (tid < 192) {
            int mm = tid / 24, c = tid % 24;
            ANL(mm, c) = AGG(mm, c) / NRM(mm);
        }
        __syncthreads();
        {
            const int n = lane;
            float pa[24]; float p2 = 0.f;
#pragma unroll
            for (int c = 0; c < 24; ++c) { pa[c] = SL(0, n, c); p2 += pa[c] * pa[c]; }
            float pinv = 1.f / (sqrtf(p2) + 1e-6f);
            float s2[8];
#pragma unroll
            for (int mm = 0; mm < 8; ++mm) {
                float dt = 0.f;
#pragma unroll
                for (int c = 0; c < 24; ++c) dt += ANL(mm, c) * pa[c];
                s2[mm] = salpha[mm] * (dt * pinv) + sbeta[mm];
            }
            float mx = s2[0];
#pragma unroll
            for (int mm = 1; mm < 8; ++mm) mx = fmaxf(mx, s2[mm]);
            float sum = 0.f;
#pragma unroll
            for (int mm = 0; mm < 8; ++mm) { s2[mm] = expf(s2[mm] - mx); sum += s2[mm]; }
            float inv = 1.f / sum;
            const int c0 = wid * 6;
#pragma unroll
            for (int cc = 0; cc < 6; ++cc) {
                int c = c0 + cc;
                float v = 0.f;
#pragma unroll
                for (int mm = 0; mm < 8; ++mm) v += AGG(mm, c) * (s2[mm] * inv);
                o8[(size_t)(Bi * NDIM + h * NHD + c) * 64 + n] = v;
            }
        }
        #undef SL
        #undef Y2S
        #undef WBM
        #undef AGG
        #undef ANL
        #undef NRM
    }
    group_barrier(cnt + 2, 16);

    // ================= Phase D: proj2 + upsample (24 o) =================
    {
        #define DAL(d,n) smem[(d)*64+(n)]              // [96][64]
        #define DWL(d,o) smem[6144+(d)*24+(o)]         // [96][24]
        #define DZT(o,n) smem[8448+(o)*65+(n)]         // [24][65]
        const int o0 = sub * 24;
#pragma unroll
        for (int i = 0; i < 6; ++i) {
            int f = tid + i * 256;
            int d = f >> 4, ng = f & 15;
            *reinterpret_cast<float4*>(&DAL(d, ng * 4)) =
                *reinterpret_cast<const float4*>(&o8[(size_t)(b * NDIM + d) * 64 + ng * 4]);
        }
        for (int idx = tid; idx < 96 * 6; idx += 256) {
            int d = idx / 6, q = idx % 6;
            *reinterpret_cast<float4*>(&DWL(d, q * 4)) =
                *reinterpret_cast<const float4*>(&W2[d * NCIN + o0 + q * 4]);
        }
        __syncthreads();
        {
            const int n = tid & 63, og = tid >> 6;
            float a0 = 0.f, a1 = 0.f, a2 = 0.f, a3 = 0.f, a4 = 0.f, a5 = 0.f;
#pragma unroll 8
            for (int d = 0; d < 96; ++d) {
                float a = DAL(d, n);
                float2 w01 = *reinterpret_cast<const float2*>(&DWL(d, og * 6 + 0));
                float2 w23 = *reinterpret_cast<const float2*>(&DWL(d, og * 6 + 2));
                float2 w45 = *reinterpret_cast<const float2*>(&DWL(d, og * 6 + 4));
                a0 += a * w01.x; a1 += a * w01.y;
                a2 += a * w23.x; a3 += a * w23.y;
                a4 += a * w45.x; a5 += a * w45.y;
            }
            DZT(og * 6 + 0, n) = a0;
            DZT(og * 6 + 1, n) = a1;
            DZT(og * 6 + 2, n) = a2;
            DZT(og * 6 + 3, n) = a3;
            DZT(og * 6 + 4, n) = a4;
            DZT(og * 6 + 5, n) = a5;
        }
        __syncthreads();
#pragma unroll
        for (int pass = 0; pass < 2; ++pass) {
            int slot = pass * 256 + tid;
            if (slot < 24 * 16) {
                const int ol = slot >> 4, xq = slot & 15;
                const float bias = b2[o0 + ol];

                float uxb = 0.125f * (float)(xq * 4) - 0.4375f;
                float uxbc = fminf(fmaxf(uxb, 0.f), 7.f);
                const int ixb = (int)uxbc;
                float wa[4], wbx[4], wc[4];
#pragma unroll
                for (int j = 0; j < 4; ++j) {
                    float ux  = 0.125f * (float)(xq * 4 + j) - 0.4375f;
                    float uxc = fminf(fmaxf(ux, 0.f), 7.f);
                    int ix0 = (int)uxc;
                    int ix1 = ix0 + 1 > 7 ? 7 : ix0 + 1;
                    float fx = uxc - (float)ix0;
                    int k0 = ix0 - ixb, k1 = ix1 - ixb;
                    wa[j]  = ((k0 == 0) ? (1.f - fx) : 0.f) + ((k1 == 0) ? fx : 0.f);
                    wbx[j] = ((k0 == 1) ? (1.f - fx) : 0.f) + ((k1 == 1) ? fx : 0.f);
                    wc[j]  = ((k1 == 2) ? fx : 0.f);
                }
                float zc0[8], zc1[8], zc2[8];
                {
                    const int i1 = ixb + 1 > 7 ? 7 : ixb + 1;
                    const int i2 = ixb + 2 > 7 ? 7 : ixb + 2;
#pragma unroll
                    for (int iy = 0; iy < 8; ++iy) {
                        zc0[iy] = DZT(ol, iy * 8 + ixb);
                        zc1[iy] = DZT(ol, iy * 8 + i1);
                        zc2[iy] = DZT(ol, iy * 8 + i2);
                    }
                }
                float* obase = out + (size_t)(b * NCIN + o0 + ol) * 4096 + xq * 4;
#pragma unroll
                for (int y = 0; y < 64; ++y) {
                    const float u  = 0.125f * (float)y - 0.4375f;
                    const float uc = fminf(fmaxf(u, 0.f), 7.f);
                    const int iy0 = (int)uc;
                    const int iy1 = iy0 + 1 > 7 ? 7 : iy0 + 1;
                    const float fy = uc - (float)iy0;
                    const float r0 = zc0[iy0] + fy * (zc0[iy1] - zc0[iy0]);
                    const float r1 = zc1[iy0] + fy * (zc1[iy1] - zc1[iy0]);
                    const float r2 = zc2[iy0] + fy * (zc2[iy1] - zc2[iy0]);
                    float4 v;
                    v.x = bias + wa[0] * r0 + wbx[0] * r1 + wc[0] * r2;
                    v.y = bias + wa[1] * r0 + wbx[1] * r1 + wc[1] * r2;
                    v.z = bias + wa[2] * r0 + wbx[2] * r1 + wc[2] * r2;
                    v.w = bias + wa[3] * r0 + wbx[3] * r1 + wc[3] * r2;
                    *reinterpret_cast<float4*>(obase + y * 64) = v;
                }
            }
        }
        #undef DAL
        #undef DWL
        #undef DZT
    }
}

// ---------------------------------------------------------------------------
extern "C" void kernel_launch(void* const* d_in, const int* in_sizes, int n_in,
                              void* d_out, int out_size, void* d_ws, size_t ws_size,
                              hipStream_t stream) {
    const float* x  = (const float*)d_in[0];
    const float* W1 = (const float*)d_in[1];
    const float* b1 = (const float*)d_in[2];
    const float* W2 = (const float*)d_in[3];
    const float* b2 = (const float*)d_in[4];
    const float* sa = (const float*)d_in[5];
    const float* sb = (const float*)d_in[6];
    float* out = (float*)d_out;

    float* x8 = (float*)d_ws;                 // 16*384*64 = 393216 f
    float* y8 = x8 + 16 * 384 * 64;           // 1024*480  = 491520 f
    float* o8 = y8 + 1024 * 480;              // 16*96*64  =  98304 f
    int* flags = (int*)(o8 + 16 * 96 * 64);   // 48 ints (16 b x 3 phases)

    hipMemsetAsync(flags, 0, 64 * sizeof(int), stream);

    void* args[] = {(void*)&x, (void*)&W1, (void*)&b1, (void*)&W2, (void*)&b2,
                    (void*)&sa, (void*)&sb, (void*)&out, (void*)&x8, (void*)&y8,
                    (void*)&o8, (void*)&flags};
    hipLaunchCooperativeKernel((const void*)k_fused, dim3(256), dim3(256),
                               args, 0, stream);
}